// Round 2
// 487.332 us; speedup vs baseline: 1.0004x; 1.0004x over previous
//
#include <hip/hip_runtime.h>

// Problem: B=32, S=4096, H=768, fp32.
// start_logits[b,s] = sum_h hidden[b,s,h] * w_start[h]
// end_logits[b,s]   = sum_h hidden[b,s,h] * w_end[h]
// Output: concat(start, end) flat -> 2*B*S floats.
//
// Memory-bound streaming reduce: 402.7 MB hidden read, 1 MB write.
// HBM floor @6.3 TB/s ~ 64 us.
//
// R1: replace the per-row 6-step __shfl_xor butterfly (12 ds_swizzle
// ops/row, 6-deep LDS-pipe dependency chain, ~100cy each, all waves
// contending on the LDS pipe) with an all-VALU DPP reduction:
//   row_shr:1/2/4/8  then row_bcast:15 (rows 1,3) + row_bcast:31 (rows 2,3)
// leaving the full 64-lane sum in lane 63. readlane(63) -> SGPR uniform,
// then `if (lane==r)` (v_cndmask; r is a compile-time unroll constant)
// parks row r's result in lane r. Zero DS ops per row.
//
// R1 compile fixes: DPP ctrl/row_mask as template constants (builtin
// requires constant integers); no writelane (not declared on this ROCm).
//
// Everything else unchanged:
//  - persistent wave64 handles 16 consecutive rows
//  - weight fragments (3x float4 each) hoisted to registers once per wave
//  - hidden loads: nontemporal float4, lane i covers elems {0,256,512}+4i
//    (fully coalesced 1 KiB/instr; nt keeps the 402 MB stream out of L2)
//  - after 16 rows, lanes 0..15 do ONE coalesced 64 B store per output.

#define ROWS (32 * 4096)       // 131072
#define HDIM 768
#define ROWS_PER_WAVE 16

typedef float f32x4 __attribute__((ext_vector_type(4)));

// v + dpp_perm(v); old=0 + bound_ctrl so masked-off/OOB lanes contribute 0.
template <int CTRL, int ROW_MASK>
__device__ __forceinline__ float dpp_add(float v) {
    int moved = __builtin_amdgcn_update_dpp(
        0, __float_as_int(v), CTRL, ROW_MASK, 0xf, true);
    return v + __int_as_float(moved);
}

// Full wave64 sum; result valid in lane 63 only. All VALU, no LDS.
__device__ __forceinline__ float wave_reduce63(float v) {
    v = dpp_add<0x111, 0xf>(v); // row_shr:1
    v = dpp_add<0x112, 0xf>(v); // row_shr:2
    v = dpp_add<0x114, 0xf>(v); // row_shr:4
    v = dpp_add<0x118, 0xf>(v); // row_shr:8 -> lane15 of each row16 has row sum
    v = dpp_add<0x142, 0xa>(v); // row_bcast:15 into rows 1,3
    v = dpp_add<0x143, 0xc>(v); // row_bcast:31 into rows 2,3 -> lane 63 total
    return v;
}

__global__ __launch_bounds__(256) void qa_logits_kernel(
    const float* __restrict__ hs,
    const float* __restrict__ w_start,
    const float* __restrict__ w_end,
    float* __restrict__ out) {

    const int lane = threadIdx.x & 63;
    const int wave = (blockIdx.x * blockDim.x + threadIdx.x) >> 6;
    const int row0 = wave * ROWS_PER_WAVE;

    // Weight fragments: constant per lane, loaded once, L1-broadcast.
    f32x4 wa[3], wb[3];
#pragma unroll
    for (int k = 0; k < 3; ++k) {
        wa[k] = *(const f32x4*)(w_start + k * 256 + lane * 4);
        wb[k] = *(const f32x4*)(w_end   + k * 256 + lane * 4);
    }

    float s_keep = 0.f, e_keep = 0.f;
    const float* __restrict__ base = hs + (size_t)row0 * HDIM + lane * 4;

#pragma unroll 4
    for (int r = 0; r < ROWS_PER_WAVE; ++r) {
        const float* __restrict__ row = base + (size_t)r * HDIM;
        float s = 0.f, e = 0.f;
#pragma unroll
        for (int k = 0; k < 3; ++k) {
            const f32x4 h = __builtin_nontemporal_load((const f32x4*)(row + k * 256));
            s += h.x * wa[k].x + h.y * wa[k].y + h.z * wa[k].z + h.w * wa[k].w;
            e += h.x * wb[k].x + h.y * wb[k].y + h.z * wb[k].z + h.w * wb[k].w;
        }
        // All-VALU reduce: sum lands in lane 63.
        s = wave_reduce63(s);
        e = wave_reduce63(e);
        // Broadcast lane63 -> SGPR (uniform); park in lane r via cndmask.
        const float ssum = __int_as_float(
            __builtin_amdgcn_readlane(__float_as_int(s), 63));
        const float esum = __int_as_float(
            __builtin_amdgcn_readlane(__float_as_int(e), 63));
        if (lane == r) { s_keep = ssum; e_keep = esum; }
    }

    // Coalesced 64 B stores: lanes 0..15 hold rows row0..row0+15.
    if (lane < ROWS_PER_WAVE) {
        out[row0 + lane] = s_keep;
        out[ROWS + row0 + lane] = e_keep;
    }
}

extern "C" void kernel_launch(void* const* d_in, const int* in_sizes, int n_in,
                              void* d_out, int out_size, void* d_ws, size_t ws_size,
                              hipStream_t stream) {
    const float* hs      = (const float*)d_in[0];
    const float* w_start = (const float*)d_in[1];
    const float* w_end   = (const float*)d_in[2];
    float* out = (float*)d_out;

    // 131072 rows / 16 rows-per-wave = 8192 waves = 2048 blocks x 4 waves.
    const int blocks = ROWS / (ROWS_PER_WAVE * 4);
    qa_logits_kernel<<<blocks, 256, 0, stream>>>(hs, w_start, w_end, out);
}